// Round 2
// baseline (358149.585 us; speedup 1.0000x reference)
//
#include <hip/hip_runtime.h>
#include <math.h>

#define TENC 400
#define TMEL 800
#define NMEL 80
#define ENCD 768
#define PRE  256
#define ARNN 1024
#define DRNN 1024
#define ATTD 128

__device__ __forceinline__ float4 ld4(const float* p){ return *(const float4*)p; }
__device__ __forceinline__ float dot4(float4 a, float4 b){
  return a.x*b.x + a.y*b.y + a.z*b.z + a.w*b.w;
}
__device__ __forceinline__ float wred(float v){
  #pragma unroll
  for (int o = 32; o > 0; o >>= 1) v += __shfl_down(v, o);
  return v;
}
__device__ __forceinline__ float sigmf(float x){ return 1.f/(1.f + __expf(-x)); }

// ---------------- prenet: xs[t][b][256] ----------------
__global__ __launch_bounds__(256) void prenet_kernel(
    const float* __restrict__ din, const float* __restrict__ w1,
    const float* __restrict__ w2, float* __restrict__ xs)
{
  int t = blockIdx.x;
  __shared__ float f_s[32*80];
  __shared__ float p_s[32*256];
  for (int id = threadIdx.x; id < 32*80; id += 256) {
    int b = id / 80, m = id - b*80;
    f_s[id] = (t == 0) ? 0.f : din[b*(NMEL*TMEL) + m*TMEL + (t-1)];
  }
  __syncthreads();
  for (int b = 0; b < 32; ++b) {
    int k = threadIdx.x;
    float acc = 0.f;
    #pragma unroll 4
    for (int m = 0; m < 80; ++m) acc += f_s[b*80+m] * w1[k*80+m];
    p_s[b*256+k] = fmaxf(acc, 0.f);
  }
  __syncthreads();
  for (int b = 0; b < 32; ++b) {
    int j = threadIdx.x;
    float acc = 0.f;
    #pragma unroll 4
    for (int kk = 0; kk < 256; ++kk) acc += p_s[b*256+kk] * w2[j*256+kk];
    xs[t*(32*256) + b*256 + j] = fmaxf(acc, 0.f);
  }
}

// ---------------- pmem[b][t][128] = memory @ mem_w^T ----------------
__global__ __launch_bounds__(256) void pmem_kernel(
  const float* __restrict__ mem, const float* __restrict__ mw, float* __restrict__ pmem)
{
  int b = blockIdx.y, tc = blockIdx.x;           // 25 chunks of 16 t'
  int a = threadIdx.x & 127, th = threadIdx.x >> 7;
  for (int i = 0; i < 8; ++i) {
    int tt = tc*16 + th + 2*i;
    const float* mrow = mem + (size_t)b*(TENC*ENCD) + (size_t)tt*ENCD;
    const float* wrow = mw + a*ENCD;
    float acc = 0.f;
    #pragma unroll 4
    for (int e4 = 0; e4 < ENCD; e4 += 4) acc += dot4(ld4(mrow+e4), ld4(wrow+e4));
    pmem[b*(TENC*ATTD) + tt*ATTD + a] = acc;
  }
}

// ---------------- projection (device helper) ----------------
__device__ __forceinline__ void proj_task(int d, const float* dh, const float* ctx,
    const float* proj_w, const float* proj_b, const float* gate_w, const float* gate_b,
    float* out_mel, float* out_gate, int t)
{
  if (d >= 32*81) return;
  int b = d / 81, r = d - b*81;
  const float* w   = (r < 80) ? (proj_w + r*1792) : gate_w;
  const float* dhr = dh + b*DRNN;
  const float* cxr = ctx + b*ENCD;
  float acc = 0.f;
  #pragma unroll 4
  for (int k = 0; k < 1024; k += 4) acc += dot4(ld4(dhr+k), ld4(w+k));
  #pragma unroll 4
  for (int k = 0; k < 768;  k += 4) acc += dot4(ld4(cxr+k), ld4(w+1024+k));
  if (r < 80) out_mel[(b*80 + r)*TMEL + t] = acc + proj_b[r];
  else        out_gate[b*TMEL + t]         = acc + gate_b[0];
}

// XCD-aware remap: blocks sharing the same weight rows (same uc, all 32 b)
// get indices congruent mod 8 -> same XCD -> weight rows fetched into ONE L2.
__device__ __forceinline__ void lstm_remap(int idx, int& b, int& uc){
  int g = idx & 7, s = idx >> 3;     // s in 0..255
  uc = g*8 + (s >> 5);               // 8 uc-groups per XCD
  b  = s & 31;
}

// ---------------- attention LSTM (+ folded projection of step t-1) ----------------
__global__ __launch_bounds__(256) void att_lstm_kernel(
  const float* __restrict__ xs_t, const float* __restrict__ ctx,
  const float* __restrict__ ah_in, float* __restrict__ ah_out, float* __restrict__ ac,
  const float* __restrict__ wih, const float* __restrict__ whh,
  const float* __restrict__ bih, const float* __restrict__ bhh,
  const float* __restrict__ dh_prev, const float* __restrict__ proj_w,
  const float* __restrict__ proj_b, const float* __restrict__ gate_w,
  const float* __restrict__ gate_b, float* __restrict__ out_mel,
  float* __restrict__ out_gate, int t)
{
  if (blockIdx.x >= 2048) {          // projection for step t-1
    if (t == 0) return;
    int d = (blockIdx.x - 2048)*256 + threadIdx.x;
    proj_task(d, dh_prev, ctx, proj_w, proj_b, gate_w, gate_b, out_mel, out_gate, t-1);
    return;
  }
  int b, uc; lstm_remap(blockIdx.x, b, uc);
  int u0 = uc * 16;
  int q = threadIdx.x >> 6, lane = threadIdx.x & 63;
  __shared__ float G[4][16];
  const float* xrow = xs_t + b*PRE;
  const float* crow = ctx  + b*ENCD;
  const float* hrow = ah_in + b*ARNN;
  for (int du = 0; du < 16; ++du) {
    int j = q*1024 + u0 + du;
    const float* wi = wih + (size_t)j*1024;
    const float* wh = whh + (size_t)j*1024;
    int kl = lane*4;
    float acc = 0.f;
    #pragma unroll
    for (int i = 0; i < 8; ++i) {
      int k = i*256 + kl;
      float4 xv, wv;
      if (i == 0)      { xv = ld4(xrow + k);          wv = ld4(wi + k); }
      else if (i < 4)  { xv = ld4(crow + (k - 256));  wv = ld4(wi + k); }
      else             { xv = ld4(hrow + (k - 1024)); wv = ld4(wh + (k - 1024)); }
      acc += dot4(xv, wv);
    }
    acc = wred(acc);
    if (lane == 0) G[q][du] = acc + bih[j] + bhh[j];
  }
  __syncthreads();
  if (threadIdx.x < 16) {
    int u = u0 + threadIdx.x;
    float gi = G[0][threadIdx.x], gf = G[1][threadIdx.x];
    float gg = G[2][threadIdx.x], go = G[3][threadIdx.x];
    float c  = ac[b*ARNN + u];
    float cn = sigmf(gf)*c + sigmf(gi)*tanhf(gg);
    ac[b*ARNN + u]     = cn;
    ah_out[b*ARNN + u] = sigmf(go)*tanhf(cn);
  }
}

// ---------------- decoder LSTM ----------------
__global__ __launch_bounds__(256) void dec_lstm_kernel(
  const float* __restrict__ ah, const float* __restrict__ ctx,
  const float* __restrict__ dh_in, float* __restrict__ dh_out, float* __restrict__ dc,
  const float* __restrict__ wih, const float* __restrict__ whh,
  const float* __restrict__ bih, const float* __restrict__ bhh)
{
  int b, uc; lstm_remap(blockIdx.x, b, uc);
  int u0 = uc * 16;
  int q = threadIdx.x >> 6, lane = threadIdx.x & 63;
  __shared__ float G[4][16];
  const float* arow = ah    + b*ARNN;
  const float* crow = ctx   + b*ENCD;
  const float* hrow = dh_in + b*DRNN;
  for (int du = 0; du < 16; ++du) {
    int j = q*1024 + u0 + du;
    const float* wi = wih + (size_t)j*1792;
    const float* wh = whh + (size_t)j*1024;
    int kl = lane*4;
    float acc = 0.f;
    #pragma unroll
    for (int i = 0; i < 11; ++i) {
      int k = i*256 + kl;
      float4 xv, wv;
      if (i < 4)       { xv = ld4(arow + k);          wv = ld4(wi + k); }
      else if (i < 7)  { xv = ld4(crow + (k - 1024)); wv = ld4(wi + k); }
      else             { xv = ld4(hrow + (k - 1792)); wv = ld4(wh + (k - 1792)); }
      acc += dot4(xv, wv);
    }
    acc = wred(acc);
    if (lane == 0) G[q][du] = acc + bih[j] + bhh[j];
  }
  __syncthreads();
  if (threadIdx.x < 16) {
    int u = u0 + threadIdx.x;
    float gi = G[0][threadIdx.x], gf = G[1][threadIdx.x];
    float gg = G[2][threadIdx.x], go = G[3][threadIdx.x];
    float c  = dc[b*DRNN + u];
    float cn = sigmf(gf)*c + sigmf(gi)*tanhf(gg);
    dc[b*DRNN + u]     = cn;
    dh_out[b*DRNN + u] = sigmf(go)*tanhf(cn);
  }
}

// ---------------- fused attention: energies + softmax + awc + ctx + align ----------------
__global__ __launch_bounds__(1024) void att_fused_kernel(
  const float* __restrict__ ah, const float* __restrict__ q_w,
  const float* __restrict__ pmem, float* __restrict__ aw_g,
  float* __restrict__ awc_g, const float* __restrict__ mem,
  const float* __restrict__ cw, const float* __restrict__ ldw,
  const float* __restrict__ vw, const int* __restrict__ mlen,
  float* __restrict__ ctx_out, float* __restrict__ out_align, int t)
{
  int b = blockIdx.x;
  int tid = threadIdx.x;
  __shared__ float loc_s[400][33];   // 52.8 KB
  __shared__ float DU[1600];         // part (pq) / epart / softmax scratch
  __shared__ float aw_s[431];        // halo'd aw, later reused as e/aw
  __shared__ float awc_s[431];
  __shared__ float pq_s[128];

  // stage aw/awc with conv halo (global t' = i - 15)
  for (int i = tid; i < 430; i += 1024) {
    int gl = i - 15;
    bool in = (gl >= 0 && gl < TENC);
    aw_s[i]  = in ? aw_g[b*TENC + gl]  : 0.f;
    awc_s[i] = in ? awc_g[b*TENC + gl] : 0.f;
  }
  // pq = ah[b] @ q_w^T  (128 outputs, K=1024 split over 8 chunks)
  {
    int a = tid & 127, kc = tid >> 7;
    const float* hr = ah + b*ARNN + kc*128;
    const float* qr = q_w + a*ARNN + kc*128;
    float acc = 0.f;
    #pragma unroll 8
    for (int k = 0; k < 128; k += 4) acc += dot4(ld4(hr+k), ld4(qr+k));
    DU[tid] = acc;
  }
  __syncthreads();
  if (tid < 128) {
    float s = 0.f;
    #pragma unroll
    for (int kc = 0; kc < 8; ++kc) s += DU[kc*128 + tid];
    pq_s[tid] = s;
  }
  // location conv: loc[t'][f]
  for (int id = tid; id < TENC*32; id += 1024) {
    int tl = id >> 5, f = id & 31;
    const float* w0 = cw + f*62;
    float acc = 0.f;
    #pragma unroll
    for (int k = 0; k < 31; ++k)
      acc += aw_s[tl+k]*w0[k] + awc_s[tl+k]*w0[31+k];
    loc_s[tl][f] = acc;
  }
  __syncthreads();
  // energies: e[t'] = sum_a vw[a]*tanh(pq[a]+pmem[t'][a]+ploc[t'][a])
  for (int base = 0; base < TENC; base += 256) {
    int tl = base + (tid >> 2), qa = tid & 3;
    if (tl < TENC) {
      const float* pm = pmem + b*(TENC*ATTD) + tl*ATTD;
      float sacc = 0.f;
      for (int a = qa*32; a < qa*32 + 32; ++a) {
        const float* lw = ldw + a*32;
        float pl = 0.f;
        #pragma unroll 8
        for (int f = 0; f < 32; ++f) pl += loc_s[tl][f] * lw[f];
        sacc += vw[a] * tanhf(pq_s[a] + pm[a] + pl);
      }
      DU[tl*4 + qa] = sacc;
    }
  }
  __syncthreads();
  int ml = mlen[b];
  if (tid < TENC) {
    float v = DU[tid*4] + DU[tid*4+1] + DU[tid*4+2] + DU[tid*4+3];
    if (tid >= ml) v = -1000000000.0f;
    aw_s[tid] = v;                       // aw_s now holds e
  }
  __syncthreads();
  // softmax over 400
  float v = (tid < TENC) ? aw_s[tid] : -3.0e38f;
  DU[tid] = v; __syncthreads();
  for (int st = 512; st > 0; st >>= 1) {
    if (tid < st) DU[tid] = fmaxf(DU[tid], DU[tid+st]);
    __syncthreads();
  }
  float mx = DU[0]; __syncthreads();
  float ex = (tid < TENC) ? __expf(v - mx) : 0.f;
  DU[tid] = ex; __syncthreads();
  for (int st = 512; st > 0; st >>= 1) {
    if (tid < st) DU[tid] += DU[tid+st];
    __syncthreads();
  }
  float inv = 1.f / DU[0];
  if (tid < TENC) {
    float a = ex * inv;
    aw_g[b*TENC + tid]  = a;
    awc_g[b*TENC + tid] += a;
    out_align[((size_t)b*TMEL + t)*TENC + tid] = a;
    aw_s[tid] = a;                       // aw_s now holds normalized aw
  }
  __syncthreads();
  // ctx[b][j] = sum_t' aw[t'] * mem[b][t'][j]
  if (tid < ENCD) {
    const float* mrow = mem + (size_t)b*(TENC*ENCD) + tid;
    float acc = 0.f;
    #pragma unroll 4
    for (int tt = 0; tt < TENC; ++tt) acc += aw_s[tt] * mrow[(size_t)tt*ENCD];
    ctx_out[b*ENCD + tid] = acc;
  }
}

// ---------------- standalone projection (final step) ----------------
__global__ __launch_bounds__(256) void proj_kernel(
  const float* __restrict__ dh, const float* __restrict__ ctx,
  const float* __restrict__ proj_w, const float* __restrict__ proj_b,
  const float* __restrict__ gate_w, const float* __restrict__ gate_b,
  float* __restrict__ out_mel, float* __restrict__ out_gate, int t)
{
  int d = blockIdx.x*256 + threadIdx.x;
  proj_task(d, dh, ctx, proj_w, proj_b, gate_w, gate_b, out_mel, out_gate, t);
}

extern "C" void kernel_launch(void* const* d_in, const int* in_sizes, int n_in,
                              void* d_out, int out_size, void* d_ws, size_t ws_size,
                              hipStream_t stream)
{
  const float* memory = (const float*)d_in[0];
  const float* din    = (const float*)d_in[1];
  const float* w1     = (const float*)d_in[3];
  const float* w2     = (const float*)d_in[4];
  const float* awih   = (const float*)d_in[5];
  const float* awhh   = (const float*)d_in[6];
  const float* abih   = (const float*)d_in[7];
  const float* abhh   = (const float*)d_in[8];
  const float* q_w    = (const float*)d_in[9];
  const float* mem_w  = (const float*)d_in[10];
  const float* v_w    = (const float*)d_in[11];
  const float* cw     = (const float*)d_in[12];
  const float* ldw    = (const float*)d_in[13];
  const float* dwih   = (const float*)d_in[14];
  const float* dwhh   = (const float*)d_in[15];
  const float* dbih   = (const float*)d_in[16];
  const float* dbhh   = (const float*)d_in[17];
  const float* pw     = (const float*)d_in[18];
  const float* pb     = (const float*)d_in[19];
  const float* gw     = (const float*)d_in[20];
  const float* gb     = (const float*)d_in[21];
  const int*   mlen   = (const int*)d_in[22];

  float* xs   = (float*)d_ws;                    // 800*32*256
  float* pmem = xs + 800*32*256;                 // 32*400*128
  float* st   = pmem + 32*400*128;
  float* ah0  = st;
  float* ah1  = ah0 + 32*1024;
  float* ac   = ah1 + 32*1024;
  float* dh0  = ac  + 32*1024;
  float* dh1  = dh0 + 32*1024;
  float* dc   = dh1 + 32*1024;
  float* ctx  = dc  + 32*1024;
  float* aw   = ctx + 32*768;
  float* awc  = aw  + 32*400;

  float* out_mel   = (float*)d_out;              // (32,80,800)
  float* out_gate  = out_mel + 32*80*800;        // (32,800)
  float* out_align = out_gate + 32*800;          // (32,800,400)

  hipMemsetAsync(st, 0, (size_t)(6*32*1024 + 32*768 + 2*32*400)*sizeof(float), stream);
  prenet_kernel<<<TMEL, 256, 0, stream>>>(din, w1, w2, xs);
  pmem_kernel<<<dim3(25,32), 256, 0, stream>>>(memory, mem_w, pmem);

  for (int t = 0; t < TMEL; ++t) {
    float* ah_in  = (t & 1) ? ah1 : ah0;
    float* ah_out = (t & 1) ? ah0 : ah1;
    float* dh_in  = (t & 1) ? dh1 : dh0;
    float* dh_out = (t & 1) ? dh0 : dh1;
    att_lstm_kernel<<<2064, 256, 0, stream>>>(xs + t*32*256, ctx, ah_in, ah_out, ac,
        awih, awhh, abih, abhh, dh_in, pw, pb, gw, gb, out_mel, out_gate, t);
    att_fused_kernel<<<32, 1024, 0, stream>>>(ah_out, q_w, pmem, aw, awc, memory,
        cw, ldw, v_w, mlen, ctx, out_align, t);
    dec_lstm_kernel<<<2048, 256, 0, stream>>>(ah_out, ctx, dh_in, dh_out, dc,
        dwih, dwhh, dbih, dbhh);
  }
  proj_kernel<<<16, 256, 0, stream>>>(dh0, ctx, pw, pb, gw, gb, out_mel, out_gate, TMEL-1);
}

// Round 6
// 281280.664 us; speedup vs baseline: 1.2733x; 1.2733x over previous
//
#include <hip/hip_runtime.h>
#include <math.h>

#define TENC 400
#define TMEL 800
#define NMEL 80
#define ENCD 768
#define PRE  256
#define ARNN 1024
#define DRNN 1024
#define ATTD 128

__device__ __forceinline__ float4 ld4(const float* p){ return *(const float4*)p; }
__device__ __forceinline__ float dot4(float4 a, float4 b){
  return a.x*b.x + a.y*b.y + a.z*b.z + a.w*b.w;
}
__device__ __forceinline__ float sigmf(float x){ return 1.f/(1.f + __expf(-x)); }

// =================== prenet: xsT[t][k=256][b=32] ===================
__global__ __launch_bounds__(256) void prenet_kernel(
    const float* __restrict__ din, const float* __restrict__ w1,
    const float* __restrict__ w2, float* __restrict__ xsT)
{
  int t = blockIdx.x;
  __shared__ float f_s[32*80];
  __shared__ float p_s[32*257];
  for (int id = threadIdx.x; id < 32*80; id += 256) {
    int b = id / 80, m = id - b*80;
    f_s[id] = (t == 0) ? 0.f : din[b*(NMEL*TMEL) + m*TMEL + (t-1)];
  }
  __syncthreads();
  for (int b = 0; b < 32; ++b) {
    int k = threadIdx.x;
    float acc = 0.f;
    #pragma unroll 4
    for (int m = 0; m < 80; ++m) acc += f_s[b*80+m] * w1[k*80+m];
    p_s[b*257+k] = fmaxf(acc, 0.f);
  }
  __syncthreads();
  int b = threadIdx.x & 31, jslot = threadIdx.x >> 5;
  for (int jj = 0; jj < 32; ++jj) {
    int j = jslot*32 + jj;
    const float* w2r = w2 + j*256;
    float acc = 0.f;
    #pragma unroll 4
    for (int kk = 0; kk < 256; ++kk) acc += p_s[b*257+kk] * w2r[kk];
    xsT[(size_t)t*8192 + j*32 + b] = fmaxf(acc, 0.f);
  }
}

// =================== pmem[b][t][128] ===================
__global__ __launch_bounds__(256) void pmem_kernel(
  const float* __restrict__ mem, const float* __restrict__ mw, float* __restrict__ pmem)
{
  int b = blockIdx.y, tc = blockIdx.x;
  int a = threadIdx.x & 127, th = threadIdx.x >> 7;
  for (int i = 0; i < 8; ++i) {
    int tt = tc*16 + th + 2*i;
    const float* mrow = mem + (size_t)b*(TENC*ENCD) + (size_t)tt*ENCD;
    const float* wrow = mw + a*ENCD;
    float acc = 0.f;
    #pragma unroll 4
    for (int e4 = 0; e4 < ENCD; e4 += 4) acc += dot4(ld4(mrow+e4), ld4(wrow+e4));
    pmem[b*(TENC*ATTD) + tt*ATTD + a] = acc;
  }
}

// =================== q_wT[k=1024][a=128] ===================
__global__ __launch_bounds__(256) void qwt_kernel(
  const float* __restrict__ qw, float* __restrict__ qwT)
{
  int a = blockIdx.x;
  for (int i = 0; i < 4; ++i) {
    int k = threadIdx.x + i*256;
    qwT[k*128 + a] = qw[a*1024 + k];
  }
}

// =================== SIMPLE GEMM: thread per (j,b) ===================
__device__ __forceinline__ void gemm_simple(int jb,
  const float* __restrict__ xtA, int nkA, const float* __restrict__ xtB, int nkB,
  const float* __restrict__ xtC, int nkC,
  const float* __restrict__ wih, int kih, const float* __restrict__ whh,
  float* __restrict__ gT)
{
  int tid = threadIdx.x;
  int j = jb*8 + (tid >> 5);
  int b = tid & 31;
  const float* wi = wih + (size_t)j*kih;
  const float* wh = whh + (size_t)j*1024;
  float acc = 0.f;
  for (int k = 0; k < nkA; ++k) acc += wi[k]        * xtA[k*32 + b];
  for (int k = 0; k < nkB; ++k) acc += wi[nkA + k]  * xtB[k*32 + b];
  for (int k = 0; k < nkC; ++k) acc += wh[k]        * xtC[k*32 + b];
  gT[(size_t)j*32 + b] = acc;
}

// =================== K_A: att-gemm (512) + dec-cell(t-1) (32) ===================
__global__ __launch_bounds__(256) void kA_kernel(
  const float* __restrict__ xsT_t, const float* __restrict__ ctxT,
  const float* __restrict__ ahT,
  const float* __restrict__ awih, const float* __restrict__ awhh,
  float* __restrict__ gaT,
  const float* __restrict__ gdT, float* __restrict__ dc,
  float* __restrict__ dh, float* __restrict__ dhT,
  const float* __restrict__ dbih, const float* __restrict__ dbhh, int t)
{
  if (blockIdx.x < 512) {
    gemm_simple(blockIdx.x, xsT_t, 256, ctxT, 768, ahT, 1024, awih, 1024, awhh, gaT);
    return;
  }
  if (t == 0) return;
  int b = blockIdx.x - 512;
  #pragma unroll
  for (int i = 0; i < 4; ++i) {
    int u = threadIdx.x + i*256;
    float gi = gdT[(size_t)(0*1024 + u)*32 + b] + dbih[0*1024+u] + dbhh[0*1024+u];
    float gf = gdT[(size_t)(1*1024 + u)*32 + b] + dbih[1*1024+u] + dbhh[1*1024+u];
    float gg = gdT[(size_t)(2*1024 + u)*32 + b] + dbih[2*1024+u] + dbhh[2*1024+u];
    float go = gdT[(size_t)(3*1024 + u)*32 + b] + dbih[3*1024+u] + dbhh[3*1024+u];
    float c  = dc[b*1024 + u];
    float cn = sigmf(gf)*c + sigmf(gi)*tanhf(gg);
    float h  = sigmf(go)*tanhf(cn);
    dc[b*1024 + u]  = cn;
    dh[b*1024 + u]  = h;
    dhT[u*32 + b]   = h;
  }
}

// =================== projection (device helper) ===================
__device__ __forceinline__ void proj_task(int d, const float* dh, const float* ctx,
    const float* proj_w, const float* proj_b, const float* gate_w, const float* gate_b,
    float* out_mel, float* out_gate, int t)
{
  if (d >= 32*81) return;
  int b = d / 81, r = d - b*81;
  const float* w   = (r < 80) ? (proj_w + r*1792) : gate_w;
  const float* dhr = dh + b*DRNN;
  const float* cxr = ctx + b*ENCD;
  float acc = 0.f;
  #pragma unroll 4
  for (int k = 0; k < 1024; k += 4) acc += dot4(ld4(dhr+k), ld4(w+k));
  #pragma unroll 4
  for (int k = 0; k < 768;  k += 4) acc += dot4(ld4(cxr+k), ld4(w+1024+k));
  if (r < 80) out_mel[(b*80 + r)*TMEL + t] = acc + proj_b[r];
  else        out_gate[b*TMEL + t]         = acc + gate_b[0];
}

// =================== K_B: att-cell + pq (32) + proj(t-1) (16) ===================
__global__ __launch_bounds__(256) void kB_kernel(
  const float* __restrict__ gaT, const float* __restrict__ ac_old,
  float* __restrict__ ac_new, float* __restrict__ ahT,
  const float* __restrict__ abih, const float* __restrict__ abhh,
  const float* __restrict__ qwT, float* __restrict__ pq_buf,
  const float* __restrict__ dh, const float* __restrict__ ctx,
  const float* __restrict__ pw, const float* __restrict__ pb,
  const float* __restrict__ gw, const float* __restrict__ gb,
  float* __restrict__ out_mel, float* __restrict__ out_gate, int t)
{
  if (blockIdx.x >= 32) {
    if (t == 0) return;
    int d = (blockIdx.x - 32)*256 + threadIdx.x;
    proj_task(d, dh, ctx, pw, pb, gw, gb, out_mel, out_gate, t-1);
    return;
  }
  int b = blockIdx.x;
  __shared__ float ah_s[1024];
  __shared__ float part[256];
  #pragma unroll
  for (int i = 0; i < 4; ++i) {
    int u = threadIdx.x + i*256;
    float gi = gaT[(size_t)(0*1024 + u)*32 + b] + abih[0*1024+u] + abhh[0*1024+u];
    float gf = gaT[(size_t)(1*1024 + u)*32 + b] + abih[1*1024+u] + abhh[1*1024+u];
    float gg = gaT[(size_t)(2*1024 + u)*32 + b] + abih[2*1024+u] + abhh[2*1024+u];
    float go = gaT[(size_t)(3*1024 + u)*32 + b] + abih[3*1024+u] + abhh[3*1024+u];
    float c  = ac_old[b*1024 + u];
    float cn = sigmf(gf)*c + sigmf(gi)*tanhf(gg);
    float h  = sigmf(go)*tanhf(cn);
    ac_new[b*1024 + u] = cn;
    ah_s[u] = h;
    ahT[u*32 + b] = h;
  }
  __syncthreads();
  int a = threadIdx.x & 127, kh = threadIdx.x >> 7;
  float acc = 0.f;
  for (int k = kh*512; k < kh*512 + 512; ++k)
    acc += ah_s[k] * qwT[k*128 + a];
  part[threadIdx.x] = acc;
  __syncthreads();
  if (threadIdx.x < 128)
    pq_buf[b*128 + threadIdx.x] = part[threadIdx.x] + part[threadIdx.x + 128];
}

// =================== K_C: energies (256 blocks) ===================
__global__ __launch_bounds__(256) void kC_kernel(
  const float* __restrict__ pq_buf, const float* __restrict__ pmem,
  const float* __restrict__ aw, const float* __restrict__ awc_old,
  const float* __restrict__ cw, const float* __restrict__ ldw,
  const float* __restrict__ vw, const int* __restrict__ mlen,
  float* __restrict__ e_out)
{
  int b = blockIdx.x >> 3, c8 = blockIdx.x & 7;
  int t0 = c8 * 50;
  __shared__ float pq_s[128];
  __shared__ float aw_s[80], awc_s[80];
  __shared__ float loc_s[50][33];
  __shared__ float epart[50][4];
  int tid = threadIdx.x;
  if (tid < 128) pq_s[tid] = pq_buf[b*128 + tid];
  // BUG FIX (rounds 3-5): halo needs 160 loader threads. Old code used
  // tid in [128,288) but the block has 256 threads -> awc_s[48..79] was
  // NEVER initialized (stale LDS). Use tid in [96,256) -> i in [0,160).
  if (tid >= 96) {
    int i = tid - 96;
    int h = (i < 80) ? i : i - 80;
    bool isC = i >= 80;
    int g = t0 - 15 + h;
    float v = (g >= 0 && g < TENC) ? (isC ? awc_old[b*TENC+g] : aw[b*TENC+g]) : 0.f;
    if (isC) awc_s[h] = v; else aw_s[h] = v;
  }
  __syncthreads();
  for (int id = tid; id < 50*32; id += 256) {
    int tl = id >> 5, f = id & 31;
    const float* w0 = cw + f*62;
    float acc = 0.f;
    #pragma unroll
    for (int k = 0; k < 31; ++k)
      acc += aw_s[tl+k]*w0[k] + awc_s[tl+k]*w0[31+k];
    loc_s[tl][f] = acc;
  }
  __syncthreads();
  if (tid < 200) {
    int tl = tid >> 2, qa = tid & 3;
    int tt = t0 + tl;
    const float* pm = pmem + b*(TENC*ATTD) + tt*ATTD;
    float s = 0.f;
    for (int a = qa*32; a < qa*32 + 32; ++a) {
      const float* lw = ldw + a*32;
      float pl = 0.f;
      #pragma unroll 8
      for (int f = 0; f < 32; ++f) pl += loc_s[tl][f] * lw[f];
      s += vw[a] * tanhf(pq_s[a] + pm[a] + pl);
    }
    epart[tl][qa] = s;
  }
  __syncthreads();
  if (tid < 50) {
    int tt = t0 + tid;
    float v = epart[tid][0]+epart[tid][1]+epart[tid][2]+epart[tid][3];
    if (tt >= mlen[b]) v = -1000000000.0f;
    e_out[b*TENC + tt] = v;
  }
}

// =================== K_D: softmax + ctx (192 blocks) ===================
__global__ __launch_bounds__(256) void kD_kernel(
  const float* __restrict__ e, float* __restrict__ aw_g,
  const float* __restrict__ awc_old, float* __restrict__ awc_new,
  const float* __restrict__ mem, float* __restrict__ ctxT,
  float* __restrict__ ctx, float* __restrict__ out_align, int t)
{
  int b = blockIdx.x / 6, ch = blockIdx.x % 6;
  int tid = threadIdx.x;
  __shared__ float red[256];
  __shared__ float aw_s[400];
  float v0 = e[b*TENC + tid];
  float v1 = (tid + 256 < TENC) ? e[b*TENC + tid + 256] : -3.0e38f;
  red[tid] = fmaxf(v0, v1); __syncthreads();
  for (int s = 128; s > 0; s >>= 1) {
    if (tid < s) red[tid] = fmaxf(red[tid], red[tid+s]);
    __syncthreads();
  }
  float mx = red[0]; __syncthreads();
  float p0 = __expf(v0 - mx);
  float p1 = (tid + 256 < TENC) ? __expf(v1 - mx) : 0.f;
  red[tid] = p0 + p1; __syncthreads();
  for (int s = 128; s > 0; s >>= 1) {
    if (tid < s) red[tid] += red[tid+s];
    __syncthreads();
  }
  float inv = 1.f / red[0];
  aw_s[tid] = p0 * inv;
  if (tid + 256 < TENC) aw_s[tid + 256] = p1 * inv;
  __syncthreads();
  int j = ch*128 + (tid & 127), h = tid >> 7;
  float acc = 0.f;
  const float* mrow = mem + (size_t)b*(TENC*ENCD) + j;
  #pragma unroll 4
  for (int tt = h*200; tt < h*200 + 200; ++tt)
    acc += aw_s[tt] * mrow[(size_t)tt*ENCD];
  red[tid] = acc; __syncthreads();
  if (h == 0) {
    float tot = red[tid] + red[tid + 128];
    ctxT[j*32 + b]  = tot;
    ctx[b*ENCD + j] = tot;
  }
  if (ch == 0) {
    for (int i = tid; i < TENC; i += 256) {
      float a = aw_s[i];
      aw_g[b*TENC + i] = a;
      awc_new[b*TENC + i] = awc_old[b*TENC + i] + a;
      out_align[((size_t)b*TMEL + t)*TENC + i] = a;
    }
  }
}

// =================== K_E: dec-gemm (512 blocks) ===================
__global__ __launch_bounds__(256) void kE_kernel(
  const float* __restrict__ ahT, const float* __restrict__ ctxT,
  const float* __restrict__ dhT,
  const float* __restrict__ dwih, const float* __restrict__ dwhh,
  float* __restrict__ gdT)
{
  gemm_simple(blockIdx.x, ahT, 1024, ctxT, 768, dhT, 1024, dwih, 1792, dwhh, gdT);
}

// =================== tail kernels ===================
__global__ __launch_bounds__(256) void dec_cell_tail(
  const float* __restrict__ gdT, float* __restrict__ dc,
  float* __restrict__ dh,
  const float* __restrict__ dbih, const float* __restrict__ dbhh)
{
  int b = blockIdx.x;
  #pragma unroll
  for (int i = 0; i < 4; ++i) {
    int u = threadIdx.x + i*256;
    float gi = gdT[(size_t)(0*1024 + u)*32 + b] + dbih[0*1024+u] + dbhh[0*1024+u];
    float gf = gdT[(size_t)(1*1024 + u)*32 + b] + dbih[1*1024+u] + dbhh[1*1024+u];
    float gg = gdT[(size_t)(2*1024 + u)*32 + b] + dbih[2*1024+u] + dbhh[2*1024+u];
    float go = gdT[(size_t)(3*1024 + u)*32 + b] + dbih[3*1024+u] + dbhh[3*1024+u];
    float c  = dc[b*1024 + u];
    float cn = sigmf(gf)*c + sigmf(gi)*tanhf(gg);
    dc[b*1024 + u] = cn;
    dh[b*1024 + u] = sigmf(go)*tanhf(cn);
  }
}

__global__ __launch_bounds__(256) void proj_tail(
  const float* __restrict__ dh, const float* __restrict__ ctx,
  const float* __restrict__ pw, const float* __restrict__ pb,
  const float* __restrict__ gw, const float* __restrict__ gb,
  float* __restrict__ out_mel, float* __restrict__ out_gate, int t)
{
  int d = blockIdx.x*256 + threadIdx.x;
  proj_task(d, dh, ctx, pw, pb, gw, gb, out_mel, out_gate, t);
}

extern "C" void kernel_launch(void* const* d_in, const int* in_sizes, int n_in,
                              void* d_out, int out_size, void* d_ws, size_t ws_size,
                              hipStream_t stream)
{
  const float* memory = (const float*)d_in[0];
  const float* din    = (const float*)d_in[1];
  const float* w1     = (const float*)d_in[3];
  const float* w2     = (const float*)d_in[4];
  const float* awih   = (const float*)d_in[5];
  const float* awhh   = (const float*)d_in[6];
  const float* abih   = (const float*)d_in[7];
  const float* abhh   = (const float*)d_in[8];
  const float* q_w    = (const float*)d_in[9];
  const float* mem_w  = (const float*)d_in[10];
  const float* v_w    = (const float*)d_in[11];
  const float* cw     = (const float*)d_in[12];
  const float* ldw    = (const float*)d_in[13];
  const float* dwih   = (const float*)d_in[14];
  const float* dwhh   = (const float*)d_in[15];
  const float* dbih   = (const float*)d_in[16];
  const float* dbhh   = (const float*)d_in[17];
  const float* pw     = (const float*)d_in[18];
  const float* pb     = (const float*)d_in[19];
  const float* gw     = (const float*)d_in[20];
  const float* gb     = (const float*)d_in[21];
  const int*   mlen   = (const int*)d_in[22];

  float* p = (float*)d_ws;
  float* xsT   = p;  p += 800*256*32;
  float* pmem  = p;  p += 32*400*128;
  float* qwT   = p;  p += 1024*128;
  float* gaT   = p;  p += 4096*32;
  float* gdT   = p;  p += 4096*32;
  // ---- zeroed state block (contiguous) ----
  float* zs    = p;
  float* ahT   = p;  p += 1024*32;
  float* dhT   = p;  p += 1024*32;
  float* dh    = p;  p += 32*1024;
  float* ctxT  = p;  p += 768*32;
  float* ctx   = p;  p += 32*768;
  float* acbuf = p;  p += 2*32*1024;
  float* dc    = p;  p += 32*1024;
  float* awcb  = p;  p += 2*32*400;
  float* aw    = p;  p += 32*400;
  size_t zcount = (size_t)(p - zs);
  // ---- end zero block ----
  float* e     = p;  p += 32*400;
  float* pq    = p;  p += 32*128;

  float* out_mel   = (float*)d_out;
  float* out_gate  = out_mel + 32*80*800;
  float* out_align = out_gate + 32*800;

  hipMemsetAsync(zs, 0, zcount*sizeof(float), stream);
  prenet_kernel<<<TMEL, 256, 0, stream>>>(din, w1, w2, xsT);
  pmem_kernel<<<dim3(25,32), 256, 0, stream>>>(memory, mem_w, pmem);
  qwt_kernel<<<128, 256, 0, stream>>>(q_w, qwT);

  for (int t = 0; t < TMEL; ++t) {
    float* ac_old  = acbuf + ((t+1)&1)*32*1024;
    float* ac_new  = acbuf + (t&1)*32*1024;
    float* awc_old = awcb  + ((t+1)&1)*32*400;
    float* awc_new = awcb  + (t&1)*32*400;
    kA_kernel<<<544, 256, 0, stream>>>(xsT + (size_t)t*8192, ctxT, ahT,
        awih, awhh, gaT, gdT, dc, dh, dhT, dbih, dbhh, t);
    kB_kernel<<<48, 256, 0, stream>>>(gaT, ac_old, ac_new, ahT, abih, abhh,
        qwT, pq, dh, ctx, pw, pb, gw, gb, out_mel, out_gate, t);
    kC_kernel<<<256, 256, 0, stream>>>(pq, pmem, aw, awc_old, cw, ldw, v_w, mlen, e);
    kD_kernel<<<192, 256, 0, stream>>>(e, aw, awc_old, awc_new, memory, ctxT, ctx,
        out_align, t);
    kE_kernel<<<512, 256, 0, stream>>>(ahT, ctxT, dhT, dwih, dwhh, gdT);
  }
  dec_cell_tail<<<32, 256, 0, stream>>>(gdT, dc, dh, dbih, dbhh);
  proj_tail<<<16, 256, 0, stream>>>(dh, ctx, pw, pb, gw, gb, out_mel, out_gate, TMEL-1);
}

// Round 7
// 199921.448 us; speedup vs baseline: 1.7915x; 1.4070x over previous
//
#include <hip/hip_runtime.h>
#include <math.h>

#define TENC 400
#define TMEL 800
#define NMEL 80
#define ENCD 768
#define PRE  256
#define ARNN 1024
#define DRNN 1024
#define ATTD 128

__device__ __forceinline__ float4 ld4(const float* p){ return *(const float4*)p; }
__device__ __forceinline__ float dot4(float4 a, float4 b){
  return a.x*b.x + a.y*b.y + a.z*b.z + a.w*b.w;
}
__device__ __forceinline__ float sigmf(float x){ return 1.f/(1.f + __expf(-x)); }

// =================== prenet: xsT[t][k=256][b=32] ===================
__global__ __launch_bounds__(256) void prenet_kernel(
    const float* __restrict__ din, const float* __restrict__ w1,
    const float* __restrict__ w2, float* __restrict__ xsT)
{
  int t = blockIdx.x;
  __shared__ float f_s[32*80];
  __shared__ float p_s[32*257];
  for (int id = threadIdx.x; id < 32*80; id += 256) {
    int b = id / 80, m = id - b*80;
    f_s[id] = (t == 0) ? 0.f : din[b*(NMEL*TMEL) + m*TMEL + (t-1)];
  }
  __syncthreads();
  for (int b = 0; b < 32; ++b) {
    int k = threadIdx.x;
    float acc = 0.f;
    #pragma unroll 4
    for (int m = 0; m < 80; ++m) acc += f_s[b*80+m] * w1[k*80+m];
    p_s[b*257+k] = fmaxf(acc, 0.f);
  }
  __syncthreads();
  int b = threadIdx.x & 31, jslot = threadIdx.x >> 5;
  for (int jj = 0; jj < 32; ++jj) {
    int j = jslot*32 + jj;
    const float* w2r = w2 + j*256;
    float acc = 0.f;
    #pragma unroll 4
    for (int kk = 0; kk < 256; ++kk) acc += p_s[b*257+kk] * w2r[kk];
    xsT[(size_t)t*8192 + j*32 + b] = fmaxf(acc, 0.f);
  }
}

// =================== pmem[b][t][128] ===================
__global__ __launch_bounds__(256) void pmem_kernel(
  const float* __restrict__ mem, const float* __restrict__ mw, float* __restrict__ pmem)
{
  int b = blockIdx.y, tc = blockIdx.x;
  int a = threadIdx.x & 127, th = threadIdx.x >> 7;
  for (int i = 0; i < 8; ++i) {
    int tt = tc*16 + th + 2*i;
    const float* mrow = mem + (size_t)b*(TENC*ENCD) + (size_t)tt*ENCD;
    const float* wrow = mw + a*ENCD;
    float acc = 0.f;
    #pragma unroll 4
    for (int e4 = 0; e4 < ENCD; e4 += 4) acc += dot4(ld4(mrow+e4), ld4(wrow+e4));
    pmem[b*(TENC*ATTD) + tt*ATTD + a] = acc;
  }
}

// =================== q_wT[k=1024][a=128] ===================
__global__ __launch_bounds__(256) void qwt_kernel(
  const float* __restrict__ qw, float* __restrict__ qwT)
{
  int a = blockIdx.x;
  for (int i = 0; i < 4; ++i) {
    int k = threadIdx.x + i*256;
    qwT[k*128 + a] = qw[a*1024 + k];
  }
}

// =================== TILED GEMM: gT[j][32] = sum_k W[j][k]*XT[k][b] ===================
// block tile: 16 rows x 32 batches, Kc=256 chunks. 256 threads.
// thread tile 8b x 8r; k-slices across lanes (klane); shfl_xor reduce.
__device__ __forceinline__ void gemm16_body(int jt,
  const float* __restrict__ xtA, int cA, const float* __restrict__ xtB, int cB,
  const float* __restrict__ xtC, int cC,
  const float* __restrict__ wih, int kih, const float* __restrict__ whh,
  float* __restrict__ gT, float4* Xs, float* Ws)
{
  const int tid = threadIdx.x;
  const int wave = tid >> 6, lane = tid & 63;
  const int klane = lane & 31, half = lane >> 5;
  const int tile = wave*2 + half;
  const int bg = tile & 3, rg = tile >> 2;
  const int b0 = bg*8, r0 = rg*8;
  float acc[8][8];
  #pragma unroll
  for (int i = 0; i < 8; ++i)
    #pragma unroll
    for (int j = 0; j < 8; ++j) acc[i][j] = 0.f;

  const int scol = tid & 7, skr = tid >> 3;       // X staging
  const int swr = tid >> 4, skk = (tid & 15)*16;  // W staging
  const int nC = cA + cB + cC;

  for (int c = 0; c < nC; ++c) {
    const float* xsrc; int ck;
    if (c < cA)            { xsrc = xtA; ck = c; }
    else if (c < cA + cB)  { xsrc = xtB; ck = c - cA; }
    else                   { xsrc = xtC; ck = c - cA - cB; }
    // stage X chunk (coalesced, XOR-swizzled LDS)
    #pragma unroll
    for (int i = 0; i < 8; ++i) {
      int k = skr + 32*i;
      float4 v = *(const float4*)(xsrc + (size_t)(ck*256 + k)*32 + scol*4);
      Xs[k*8 + (scol ^ (k & 7))] = v;
    }
    // stage W chunk (row-major, padded 264)
    {
      int j = jt*16 + swr;
      int kglob = c*256 + skk;
      const float* wr = (kglob < kih) ? (wih + (size_t)j*kih + kglob)
                                      : (whh + (size_t)j*1024 + (kglob - kih));
      float* wd = Ws + swr*264 + skk;
      #pragma unroll
      for (int q = 0; q < 4; ++q) *(float4*)(wd + q*4) = ld4(wr + q*4);
    }
    __syncthreads();
    #pragma unroll
    for (int kk = 0; kk < 8; ++kk) {
      int k = klane + 32*kk;
      float4 x0 = Xs[k*8 + ((bg*2)     ^ (klane & 7))];
      float4 x1 = Xs[k*8 + ((bg*2 + 1) ^ (klane & 7))];
      float w[8];
      #pragma unroll
      for (int r = 0; r < 8; ++r) w[r] = Ws[(r0 + r)*264 + k];
      float xb[8] = {x0.x, x0.y, x0.z, x0.w, x1.x, x1.y, x1.z, x1.w};
      #pragma unroll
      for (int r = 0; r < 8; ++r)
        #pragma unroll
        for (int bb = 0; bb < 8; ++bb)
          acc[bb][r] += xb[bb] * w[r];
    }
    __syncthreads();
  }
  // reduce over klane (masks <32: stays within each tile's 32 lanes)
  #pragma unroll
  for (int m = 16; m >= 1; m >>= 1)
    #pragma unroll
    for (int bb = 0; bb < 8; ++bb)
      #pragma unroll
      for (int r = 0; r < 8; ++r)
        acc[bb][r] += __shfl_xor(acc[bb][r], m);
  if (klane == 0) {
    int j0 = jt*16 + r0;
    #pragma unroll
    for (int r = 0; r < 8; ++r) {
      float4 lo = make_float4(acc[0][r], acc[1][r], acc[2][r], acc[3][r]);
      float4 hi = make_float4(acc[4][r], acc[5][r], acc[6][r], acc[7][r]);
      *(float4*)(gT + (size_t)(j0 + r)*32 + b0)     = lo;
      *(float4*)(gT + (size_t)(j0 + r)*32 + b0 + 4) = hi;
    }
  }
}

// =================== K_A: att-gemm (256) + dec-cell(t-1) (32) ===================
__global__ __launch_bounds__(256, 2) void kA_kernel(
  const float* __restrict__ xsT_t, const float* __restrict__ ctxT,
  const float* __restrict__ ahT,
  const float* __restrict__ awih, const float* __restrict__ awhh,
  float* __restrict__ gaT,
  const float* __restrict__ gdT, float* __restrict__ dc,
  float* __restrict__ dh, float* __restrict__ dhT,
  const float* __restrict__ dbih, const float* __restrict__ dbhh, int t)
{
  __shared__ float4 Xs[2048];
  __shared__ float  Ws[16*264];
  if (blockIdx.x < 256) {
    gemm16_body(blockIdx.x, xsT_t, 1, ctxT, 3, ahT, 4, awih, 1024, awhh, gaT, Xs, Ws);
    return;
  }
  if (t == 0) return;
  int b = blockIdx.x - 256;
  #pragma unroll
  for (int i = 0; i < 4; ++i) {
    int u = threadIdx.x + i*256;
    float gi = gdT[(size_t)(0*1024 + u)*32 + b] + dbih[0*1024+u] + dbhh[0*1024+u];
    float gf = gdT[(size_t)(1*1024 + u)*32 + b] + dbih[1*1024+u] + dbhh[1*1024+u];
    float gg = gdT[(size_t)(2*1024 + u)*32 + b] + dbih[2*1024+u] + dbhh[2*1024+u];
    float go = gdT[(size_t)(3*1024 + u)*32 + b] + dbih[3*1024+u] + dbhh[3*1024+u];
    float c  = dc[b*1024 + u];
    float cn = sigmf(gf)*c + sigmf(gi)*tanhf(gg);
    float h  = sigmf(go)*tanhf(cn);
    dc[b*1024 + u]  = cn;
    dh[b*1024 + u]  = h;
    dhT[u*32 + b]   = h;
  }
}

// =================== projection (device helper) ===================
__device__ __forceinline__ void proj_task(int d, const float* dh, const float* ctx,
    const float* proj_w, const float* proj_b, const float* gate_w, const float* gate_b,
    float* out_mel, float* out_gate, int t)
{
  if (d >= 32*81) return;
  int b = d / 81, r = d - b*81;
  const float* w   = (r < 80) ? (proj_w + r*1792) : gate_w;
  const float* dhr = dh + b*DRNN;
  const float* cxr = ctx + b*ENCD;
  float acc = 0.f;
  #pragma unroll 4
  for (int k = 0; k < 1024; k += 4) acc += dot4(ld4(dhr+k), ld4(w+k));
  #pragma unroll 4
  for (int k = 0; k < 768;  k += 4) acc += dot4(ld4(cxr+k), ld4(w+1024+k));
  if (r < 80) out_mel[(b*80 + r)*TMEL + t] = acc + proj_b[r];
  else        out_gate[b*TMEL + t]         = acc + gate_b[0];
}

// =================== K_B: att-cell + pq (32) + proj(t-1) (16) ===================
__global__ __launch_bounds__(256) void kB_kernel(
  const float* __restrict__ gaT, const float* __restrict__ ac_old,
  float* __restrict__ ac_new, float* __restrict__ ahT,
  const float* __restrict__ abih, const float* __restrict__ abhh,
  const float* __restrict__ qwT, float* __restrict__ pq_buf,
  const float* __restrict__ dh, const float* __restrict__ ctx,
  const float* __restrict__ pw, const float* __restrict__ pb,
  const float* __restrict__ gw, const float* __restrict__ gb,
  float* __restrict__ out_mel, float* __restrict__ out_gate, int t)
{
  if (blockIdx.x >= 32) {
    if (t == 0) return;
    int d = (blockIdx.x - 32)*256 + threadIdx.x;
    proj_task(d, dh, ctx, pw, pb, gw, gb, out_mel, out_gate, t-1);
    return;
  }
  int b = blockIdx.x;
  __shared__ float ah_s[1024];
  __shared__ float part[256];
  #pragma unroll
  for (int i = 0; i < 4; ++i) {
    int u = threadIdx.x + i*256;
    float gi = gaT[(size_t)(0*1024 + u)*32 + b] + abih[0*1024+u] + abhh[0*1024+u];
    float gf = gaT[(size_t)(1*1024 + u)*32 + b] + abih[1*1024+u] + abhh[1*1024+u];
    float gg = gaT[(size_t)(2*1024 + u)*32 + b] + abih[2*1024+u] + abhh[2*1024+u];
    float go = gaT[(size_t)(3*1024 + u)*32 + b] + abih[3*1024+u] + abhh[3*1024+u];
    float c  = ac_old[b*1024 + u];
    float cn = sigmf(gf)*c + sigmf(gi)*tanhf(gg);
    float h  = sigmf(go)*tanhf(cn);
    ac_new[b*1024 + u] = cn;
    ah_s[u] = h;
    ahT[u*32 + b] = h;
  }
  __syncthreads();
  int a = threadIdx.x & 127, kh = threadIdx.x >> 7;
  float acc = 0.f;
  for (int k = kh*512; k < kh*512 + 512; ++k)
    acc += ah_s[k] * qwT[k*128 + a];
  part[threadIdx.x] = acc;
  __syncthreads();
  if (threadIdx.x < 128)
    pq_buf[b*128 + threadIdx.x] = part[threadIdx.x] + part[threadIdx.x + 128];
}

// =================== K_C: energies (256 blocks) ===================
__global__ __launch_bounds__(256) void kC_kernel(
  const float* __restrict__ pq_buf, const float* __restrict__ pmem,
  const float* __restrict__ aw, const float* __restrict__ awc_old,
  const float* __restrict__ cw, const float* __restrict__ ldw,
  const float* __restrict__ vw, const int* __restrict__ mlen,
  float* __restrict__ e_out)
{
  int b = blockIdx.x >> 3, c8 = blockIdx.x & 7;
  int t0 = c8 * 50;
  __shared__ float pq_s[128];
  __shared__ float aw_s[80], awc_s[80];
  __shared__ float loc_s[50][33];
  __shared__ float epart[50][4];
  int tid = threadIdx.x;
  if (tid < 128) pq_s[tid] = pq_buf[b*128 + tid];
  // halo: 160 loader threads, tid in [96,256) -> i in [0,160)
  if (tid >= 96) {
    int i = tid - 96;
    int h = (i < 80) ? i : i - 80;
    bool isC = i >= 80;
    int g = t0 - 15 + h;
    float v = (g >= 0 && g < TENC) ? (isC ? awc_old[b*TENC+g] : aw[b*TENC+g]) : 0.f;
    if (isC) awc_s[h] = v; else aw_s[h] = v;
  }
  __syncthreads();
  for (int id = tid; id < 50*32; id += 256) {
    int tl = id >> 5, f = id & 31;
    const float* w0 = cw + f*62;
    float acc = 0.f;
    #pragma unroll
    for (int k = 0; k < 31; ++k)
      acc += aw_s[tl+k]*w0[k] + awc_s[tl+k]*w0[31+k];
    loc_s[tl][f] = acc;
  }
  __syncthreads();
  if (tid < 200) {
    int tl = tid >> 2, qa = tid & 3;
    int tt = t0 + tl;
    const float* pm = pmem + b*(TENC*ATTD) + tt*ATTD;
    float s = 0.f;
    for (int a = qa*32; a < qa*32 + 32; ++a) {
      const float* lw = ldw + a*32;
      float pl = 0.f;
      #pragma unroll 8
      for (int f = 0; f < 32; ++f) pl += loc_s[tl][f] * lw[f];
      s += vw[a] * tanhf(pq_s[a] + pm[a] + pl);
    }
    epart[tl][qa] = s;
  }
  __syncthreads();
  if (tid < 50) {
    int tt = t0 + tid;
    float v = epart[tid][0]+epart[tid][1]+epart[tid][2]+epart[tid][3];
    if (tt >= mlen[b]) v = -1000000000.0f;
    e_out[b*TENC + tt] = v;
  }
}

// =================== K_D: softmax + ctx (192 blocks) ===================
__global__ __launch_bounds__(256) void kD_kernel(
  const float* __restrict__ e, float* __restrict__ aw_g,
  const float* __restrict__ awc_old, float* __restrict__ awc_new,
  const float* __restrict__ mem, float* __restrict__ ctxT,
  float* __restrict__ ctx, float* __restrict__ out_align, int t)
{
  int b = blockIdx.x / 6, ch = blockIdx.x % 6;
  int tid = threadIdx.x;
  __shared__ float red[256];
  __shared__ float aw_s[400];
  float v0 = e[b*TENC + tid];
  float v1 = (tid + 256 < TENC) ? e[b*TENC + tid + 256] : -3.0e38f;
  red[tid] = fmaxf(v0, v1); __syncthreads();
  for (int s = 128; s > 0; s >>= 1) {
    if (tid < s) red[tid] = fmaxf(red[tid], red[tid+s]);
    __syncthreads();
  }
  float mx = red[0]; __syncthreads();
  float p0 = __expf(v0 - mx);
  float p1 = (tid + 256 < TENC) ? __expf(v1 - mx) : 0.f;
  red[tid] = p0 + p1; __syncthreads();
  for (int s = 128; s > 0; s >>= 1) {
    if (tid < s) red[tid] += red[tid+s];
    __syncthreads();
  }
  float inv = 1.f / red[0];
  aw_s[tid] = p0 * inv;
  if (tid + 256 < TENC) aw_s[tid + 256] = p1 * inv;
  __syncthreads();
  int j = ch*128 + (tid & 127), h = tid >> 7;
  float acc = 0.f;
  const float* mrow = mem + (size_t)b*(TENC*ENCD) + j;
  #pragma unroll 4
  for (int tt = h*200; tt < h*200 + 200; ++tt)
    acc += aw_s[tt] * mrow[(size_t)tt*ENCD];
  red[tid] = acc; __syncthreads();
  if (h == 0) {
    float tot = red[tid] + red[tid + 128];
    ctxT[j*32 + b]  = tot;
    ctx[b*ENCD + j] = tot;
  }
  if (ch == 0) {
    for (int i = tid; i < TENC; i += 256) {
      float a = aw_s[i];
      aw_g[b*TENC + i] = a;
      awc_new[b*TENC + i] = awc_old[b*TENC + i] + a;
      out_align[((size_t)b*TMEL + t)*TENC + i] = a;
    }
  }
}

// =================== K_E: dec-gemm (256 blocks) ===================
__global__ __launch_bounds__(256, 2) void kE_kernel(
  const float* __restrict__ ahT, const float* __restrict__ ctxT,
  const float* __restrict__ dhT,
  const float* __restrict__ dwih, const float* __restrict__ dwhh,
  float* __restrict__ gdT)
{
  __shared__ float4 Xs[2048];
  __shared__ float  Ws[16*264];
  gemm16_body(blockIdx.x, ahT, 4, ctxT, 3, dhT, 4, dwih, 1792, dwhh, gdT, Xs, Ws);
}

// =================== tail kernels ===================
__global__ __launch_bounds__(256) void dec_cell_tail(
  const float* __restrict__ gdT, float* __restrict__ dc,
  float* __restrict__ dh,
  const float* __restrict__ dbih, const float* __restrict__ dbhh)
{
  int b = blockIdx.x;
  #pragma unroll
  for (int i = 0; i < 4; ++i) {
    int u = threadIdx.x + i*256;
    float gi = gdT[(size_t)(0*1024 + u)*32 + b] + dbih[0*1024+u] + dbhh[0*1024+u];
    float gf = gdT[(size_t)(1*1024 + u)*32 + b] + dbih[1*1024+u] + dbhh[1*1024+u];
    float gg = gdT[(size_t)(2*1024 + u)*32 + b] + dbih[2*1024+u] + dbhh[2*1024+u];
    float go = gdT[(size_t)(3*1024 + u)*32 + b] + dbih[3*1024+u] + dbhh[3*1024+u];
    float c  = dc[b*1024 + u];
    float cn = sigmf(gf)*c + sigmf(gi)*tanhf(gg);
    dc[b*1024 + u] = cn;
    dh[b*1024 + u] = sigmf(go)*tanhf(cn);
  }
}

__global__ __launch_bounds__(256) void proj_tail(
  const float* __restrict__ dh, const float* __restrict__ ctx,
  const float* __restrict__ pw, const float* __restrict__ pb,
  const float* __restrict__ gw, const float* __restrict__ gb,
  float* __restrict__ out_mel, float* __restrict__ out_gate, int t)
{
  int d = blockIdx.x*256 + threadIdx.x;
  proj_task(d, dh, ctx, pw, pb, gw, gb, out_mel, out_gate, t);
}

extern "C" void kernel_launch(void* const* d_in, const int* in_sizes, int n_in,
                              void* d_out, int out_size, void* d_ws, size_t ws_size,
                              hipStream_t stream)
{
  const float* memory = (const float*)d_in[0];
  const float* din    = (const float*)d_in[1];
  const float* w1     = (const float*)d_in[3];
  const float* w2     = (const float*)d_in[4];
  const float* awih   = (const float*)d_in[5];
  const float* awhh   = (const float*)d_in[6];
  const float* abih   = (const float*)d_in[7];
  const float* abhh   = (const float*)d_in[8];
  const float* q_w    = (const float*)d_in[9];
  const float* mem_w  = (const float*)d_in[10];
  const float* v_w    = (const float*)d_in[11];
  const float* cw     = (const float*)d_in[12];
  const float* ldw    = (const float*)d_in[13];
  const float* dwih   = (const float*)d_in[14];
  const float* dwhh   = (const float*)d_in[15];
  const float* dbih   = (const float*)d_in[16];
  const float* dbhh   = (const float*)d_in[17];
  const float* pw     = (const float*)d_in[18];
  const float* pb     = (const float*)d_in[19];
  const float* gw     = (const float*)d_in[20];
  const float* gb     = (const float*)d_in[21];
  const int*   mlen   = (const int*)d_in[22];

  float* p = (float*)d_ws;
  float* xsT   = p;  p += 800*256*32;
  float* pmem  = p;  p += 32*400*128;
  float* qwT   = p;  p += 1024*128;
  float* gaT   = p;  p += 4096*32;
  float* gdT   = p;  p += 4096*32;
  // ---- zeroed state block (contiguous) ----
  float* zs    = p;
  float* ahT   = p;  p += 1024*32;
  float* dhT   = p;  p += 1024*32;
  float* dh    = p;  p += 32*1024;
  float* ctxT  = p;  p += 768*32;
  float* ctx   = p;  p += 32*768;
  float* acbuf = p;  p += 2*32*1024;
  float* dc    = p;  p += 32*1024;
  float* awcb  = p;  p += 2*32*400;
  float* aw    = p;  p += 32*400;
  size_t zcount = (size_t)(p - zs);
  // ---- end zero block ----
  float* e     = p;  p += 32*400;
  float* pq    = p;  p += 32*128;

  float* out_mel   = (float*)d_out;
  float* out_gate  = out_mel + 32*80*800;
  float* out_align = out_gate + 32*800;

  hipMemsetAsync(zs, 0, zcount*sizeof(float), stream);
  prenet_kernel<<<TMEL, 256, 0, stream>>>(din, w1, w2, xsT);
  pmem_kernel<<<dim3(25,32), 256, 0, stream>>>(memory, mem_w, pmem);
  qwt_kernel<<<128, 256, 0, stream>>>(q_w, qwT);

  for (int t = 0; t < TMEL; ++t) {
    float* ac_old  = acbuf + ((t+1)&1)*32*1024;
    float* ac_new  = acbuf + (t&1)*32*1024;
    float* awc_old = awcb  + ((t+1)&1)*32*400;
    float* awc_new = awcb  + (t&1)*32*400;
    kA_kernel<<<288, 256, 0, stream>>>(xsT + (size_t)t*8192, ctxT, ahT,
        awih, awhh, gaT, gdT, dc, dh, dhT, dbih, dbhh, t);
    kB_kernel<<<48, 256, 0, stream>>>(gaT, ac_old, ac_new, ahT, abih, abhh,
        qwT, pq, dh, ctx, pw, pb, gw, gb, out_mel, out_gate, t);
    kC_kernel<<<256, 256, 0, stream>>>(pq, pmem, aw, awc_old, cw, ldw, v_w, mlen, e);
    kD_kernel<<<192, 256, 0, stream>>>(e, aw, awc_old, awc_new, memory, ctxT, ctx,
        out_align, t);
    kE_kernel<<<256, 256, 0, stream>>>(ahT, ctxT, dhT, dwih, dwhh, gdT);
  }
  dec_cell_tail<<<32, 256, 0, stream>>>(gdT, dc, dh, dbih, dbhh);
  proj_tail<<<16, 256, 0, stream>>>(dh, ctx, pw, pb, gw, gb, out_mel, out_gate, TMEL-1);
}